// Round 13
// baseline (230.148 us; speedup 1.0000x reference)
//
#include <hip/hip_runtime.h>
#include <hip/hip_bf16.h>

typedef unsigned short u16;
typedef unsigned int   u32;
typedef u16 u16x8 __attribute__((ext_vector_type(8)));
typedef u16 u16x4 __attribute__((ext_vector_type(4)));
typedef float f32x4 __attribute__((ext_vector_type(4)));
typedef short s16x8 __attribute__((ext_vector_type(8)));
typedef u32 u32x4 __attribute__((ext_vector_type(4)));

__device__ __forceinline__ float b2f(u16 u) { return __uint_as_float(((u32)u) << 16); }
__device__ __forceinline__ u16 f2b(float f) {
  u32 u = __float_as_uint(f);
  u32 r = u + 0x7FFFu + ((u >> 16) & 1u);
  return (u16)(r >> 16);
}
__device__ __forceinline__ u32 f2b2(float lo, float hi) {
  __hip_bfloat162 h = __float22bfloat162_rn(make_float2(lo, hi));
  union { __hip_bfloat162 h; u32 u; } cv;
  cv.h = h;
  return cv.u;
}

#define MFMA_B16(A, B, C) __builtin_amdgcn_mfma_f32_16x16x32_bf16((A), (B), (C), 0, 0, 0)

// async global->LDS, 16B per lane; LDS dest is wave-uniform base + lane*16.
__device__ __forceinline__ void gl16(const u16* g, u16* l) {
  __builtin_amdgcn_global_load_lds(
      (const __attribute__((address_space(1))) void*)g,
      (__attribute__((address_space(3))) void*)l, 16, 0, 0);
}

// ---------------------------------------------------------------------------
// fp32 -> bf16 convert pass (cvt_w folded in at blocks >= 3200). R8-exact.
// ---------------------------------------------------------------------------
__global__ __launch_bounds__(256) void cvt_all(
    const float* __restrict__ mems, const float* __restrict__ w,
    const float* __restrict__ r, const float* __restrict__ qkvW,
    const float* __restrict__ rW, const float* __restrict__ oW,
    const float* __restrict__ cqw, const float* __restrict__ ckw,
    const float* __restrict__ cvw,
    u16* __restrict__ catb, u16* __restrict__ rb, u16* __restrict__ qkvWb,
    u16* __restrict__ rWb, u16* __restrict__ oWb, u16* __restrict__ cwb) {
  if (blockIdx.x >= 3200) {
    int idx = (blockIdx.x - 3200) * 256 + threadIdx.x;   // 0..86015
    if (idx >= 86016) return;
    int wsel = idx / 28672, rem = idx % 28672;
    const float* src = (wsel == 0) ? cqw : ((wsel == 1) ? ckw : cvw);
    int s = rem / 4096, r2 = rem % 4096;
    int d = r2 / 64, eswz = r2 % 64;
    int e = (((eswz >> 3) ^ (d & 7)) << 3) + (eswz & 7);
    cwb[idx] = f2b(src[d * 448 + e * 7 + s]);
    return;
  }
  long g = ((long)blockIdx.x * 256 + threadIdx.x) * 8;
  const float* src;
  u16* dst;
  if (g < 4194304) {
    src = (g < 2097152) ? (mems + g) : (w + (g - 2097152));
    dst = catb + g;
  } else if (g < 5242880) {
    src = r + (g - 4194304);    dst = rb + (g - 4194304);
  } else if (g < 6029312) {
    src = qkvW + (g - 5242880); dst = qkvWb + (g - 5242880);
  } else if (g < 6291456) {
    src = rW + (g - 6029312);   dst = rWb + (g - 6029312);
  } else {
    src = oW + (g - 6291456);   dst = oWb + (g - 6291456);
  }
  f32x4 a = *(const f32x4*)src;
  f32x4 b = *(const f32x4*)(src + 4);
  u32x4 p = (u32x4){f2b2(a[0], a[1]), f2b2(a[2], a[3]),
                    f2b2(b[0], b[1]), f2b2(b[2], b[3])};
  *(u32x4*)dst = p;
}

// ---------------------------------------------------------------------------
// Fused MFMA GEMM (R8-exact): 128x128 tiles, global_load_lds staging, q-skip.
// ---------------------------------------------------------------------------
__global__ __launch_bounds__(256) void gemm_fused(
    const u16* __restrict__ catb, const u16* __restrict__ qkvWb,
    u16* __restrict__ Wh, const u16* __restrict__ rb,
    const u16* __restrict__ rWb, u16* __restrict__ Rk) {
  int bx = blockIdx.x, by = blockIdx.y;
  const u16 *A, *B;
  u16* C;
  int N;
  if (bx < 12) {
    if (bx < 4 && by < 32) return;   // q-cols of mems rows never read
    A = catb; B = qkvWb; C = Wh; N = 1536;
  } else {
    if (by >= 16) return;
    A = rb; B = rWb; C = Rk; N = 512; bx = 0;
  }
  const int K = 512;
  __shared__ u16 A_s[128 * 32];
  __shared__ u16 B_s[128 * 32];
  int tid = threadIdx.x;
  int wave = tid >> 6, lane = tid & 63, quad = lane >> 4, l16 = lane & 15;
  int wr = wave >> 1, wc = wave & 1;

  f32x4 acc[4][4];
#pragma unroll
  for (int a = 0; a < 4; a++)
#pragma unroll
    for (int bb = 0; bb < 4; bb++) acc[a][bb] = (f32x4){0.f, 0.f, 0.f, 0.f};

  const u16* Ab = A + (size_t)by * 128 * K;
  const u16* Bb = B + (size_t)bx * 128 * K;
  int lrow = lane >> 2;
  int lkc  = (lane & 3) * 8;
  int L0 = wave * 2;

  for (int k0 = 0; k0 < K; k0 += 32) {
    __syncthreads();
#pragma unroll
    for (int m = 0; m < 2; m++) {
      int L = L0 + m;
      int row = L * 16 + lrow;
      gl16(Ab + (size_t)row * K + k0 + lkc, &A_s[L * 512 + lane * 8]);
      gl16(Bb + (size_t)row * K + k0 + lkc, &B_s[L * 512 + lane * 8]);
    }
    __syncthreads();

    s16x8 af[4], bf[4];
#pragma unroll
    for (int a = 0; a < 4; a++)
      af[a] = *(const s16x8*)&A_s[(wr * 64 + a * 16 + l16) * 32 + quad * 8];
#pragma unroll
    for (int bb = 0; bb < 4; bb++)
      bf[bb] = *(const s16x8*)&B_s[(wc * 64 + bb * 16 + l16) * 32 + quad * 8];
#pragma unroll
    for (int a = 0; a < 4; a++)
#pragma unroll
      for (int bb = 0; bb < 4; bb++)
        acc[a][bb] = MFMA_B16(af[a], bf[bb], acc[a][bb]);
  }

#pragma unroll
  for (int a = 0; a < 4; a++)
#pragma unroll
    for (int bb = 0; bb < 4; bb++) {
      int row = by * 128 + wr * 64 + a * 16 + quad * 4;
      int col = bx * 128 + wc * 64 + bb * 16 + l16;
#pragma unroll
      for (int reg = 0; reg < 4; reg++)
        C[(size_t)(row + reg) * N + col] = f2b(acc[a][bb][reg]);
    }
}

// ---------------------------------------------------------------------------
// Fused o-proj GEMM + LayerNorm (R22): block = 16 rows x full 512 cols,
// grid 256. Each block holds COMPLETE output rows -> LN fused in epilogue
// (per-row sum/sumsq: shfl over 16 col-lanes + 4-wave LDS combine).
// Removes the lnorm launch and the 4MB aout round-trip. Consumer of attn;
// cannot perturb attn inputs. B (oWb, 512KB) is L2-resident.
// ---------------------------------------------------------------------------
__global__ __launch_bounds__(256) void oproj_ln(
    const u16* __restrict__ av, const u16* __restrict__ oWb,
    const float* __restrict__ w, const float* __restrict__ lng,
    const float* __restrict__ lnb, float* __restrict__ out) {
  __shared__ u16 A_s[16 * 32];
  __shared__ u16 B_s[512 * 32];
  __shared__ float red_s[2][16][4];
  int tid = threadIdx.x;
  int by = blockIdx.x;                 // rows [by*16, by*16+16)
  int wave = tid >> 6, lane = tid & 63, quad = lane >> 4, l16 = lane & 15;

  f32x4 acc[8];
#pragma unroll
  for (int f = 0; f < 8; f++) acc[f] = (f32x4){0.f, 0.f, 0.f, 0.f};

  const u16* Ab = av + (size_t)by * 16 * 512;
  for (int k0 = 0; k0 < 512; k0 += 32) {
    __syncthreads();
    if (wave == 0) {
      // A: 16 rows x 32k; lane covers row tid>>2, k-slice (tid&3)*8
      gl16(Ab + (size_t)(lane >> 2) * 512 + k0 + (lane & 3) * 8, &A_s[lane * 8]);
    }
#pragma unroll
    for (int rr = 0; rr < 8; rr++) {
      int row = (tid >> 2) + rr * 64;
      gl16(oWb + (size_t)row * 512 + k0 + (tid & 3) * 8,
           &B_s[row * 32 + (tid & 3) * 8]);
    }
    __syncthreads();

    s16x8 af = *(const s16x8*)&A_s[l16 * 32 + quad * 8];
#pragma unroll
    for (int f = 0; f < 8; f++) {
      int col = wave * 128 + f * 16 + l16;
      s16x8 bf = *(const s16x8*)&B_s[col * 32 + quad * 8];
      acc[f] = MFMA_B16(af, bf, acc[f]);
    }
  }

  // epilogue: x = w + acc; per-row LN over 512 cols
  int rowb = by * 16;
  float xs[8][4];
  float psum[4] = {0.f, 0.f, 0.f, 0.f};
  float psq[4]  = {0.f, 0.f, 0.f, 0.f};
#pragma unroll
  for (int f = 0; f < 8; f++) {
    int col = wave * 128 + f * 16 + l16;
#pragma unroll
    for (int reg = 0; reg < 4; reg++) {
      int row = rowb + quad * 4 + reg;
      float x = w[(size_t)row * 512 + col] + acc[f][reg];
      xs[f][reg] = x;
      psum[reg] += x;
      psq[reg]  += x * x;
    }
  }
#pragma unroll
  for (int off = 1; off < 16; off <<= 1)
#pragma unroll
    for (int reg = 0; reg < 4; reg++) {
      psum[reg] += __shfl_xor(psum[reg], off);
      psq[reg]  += __shfl_xor(psq[reg], off);
    }
  if (l16 == 0) {
#pragma unroll
    for (int reg = 0; reg < 4; reg++) {
      red_s[0][quad * 4 + reg][wave] = psum[reg];
      red_s[1][quad * 4 + reg][wave] = psq[reg];
    }
  }
  __syncthreads();

  float mu[4], rs[4];
#pragma unroll
  for (int reg = 0; reg < 4; reg++) {
    int rw = quad * 4 + reg;
    float s  = red_s[0][rw][0] + red_s[0][rw][1] + red_s[0][rw][2] + red_s[0][rw][3];
    float sq = red_s[1][rw][0] + red_s[1][rw][1] + red_s[1][rw][2] + red_s[1][rw][3];
    float m = s * (1.0f / 512.0f);
    float v = sq * (1.0f / 512.0f) - m * m;
    mu[reg] = m;
    rs[reg] = rsqrtf(v + 1e-5f);
  }

#pragma unroll
  for (int f = 0; f < 8; f++) {
    int col = wave * 128 + f * 16 + l16;
    float gv = lng[col], bv = lnb[col];
#pragma unroll
    for (int reg = 0; reg < 4; reg++) {
      int row = rowb + quad * 4 + reg;
      out[(size_t)row * 512 + col] = (xs[f][reg] - mu[reg]) * rs[reg] * gv + bv;
    }
  }
}

// ---------------------------------------------------------------------------
// Fused MFMA conv (R8-exact: weights staged once, 4 t-chunks/block,
// grid (10,4,8)).
// ---------------------------------------------------------------------------
__global__ __launch_bounds__(256) void conv_fused(
    const u16* __restrict__ Wh, const u16* __restrict__ cwb,
    const float* __restrict__ cqb, const float* __restrict__ ckb,
    const float* __restrict__ cvb,
    u16* __restrict__ qpost, u16* __restrict__ kpost, u16* __restrict__ vpostT) {
  __shared__ u16 wT_s[7 * 4096];
  __shared__ u16 in_s[134 * 64];   // input window; reused as v-transpose T
  int blk = blockIdx.x;
  int part, lt0, len, tshift, vt;
  const float* cbp;
  const u16* cwp;
  u16* outp;
  if (blk < 2) {
    part = 0; lt0 = blk * 4; len = 1024; tshift = 1024; vt = 0;
    cbp = cqb; cwp = cwb; outp = qpost;
  } else if (blk < 6) {
    part = 1; lt0 = (blk - 2) * 4; len = 2048; tshift = 0; vt = 0;
    cbp = ckb; cwp = cwb + 28672; outp = kpost;
  } else {
    part = 2; lt0 = (blk - 6) * 4; len = 2048; tshift = 0; vt = 1;
    cbp = cvb; cwp = cwb + 57344; outp = vpostT;
  }
  int tid = threadIdx.x;
  int b = blockIdx.y, n = blockIdx.z;
  int wave = tid >> 6, lane = tid & 63, quad = lane >> 4, l16 = lane & 15;

  for (int idx = tid * 8; idx < 28672; idx += 2048)
    *(u16x8*)&wT_s[idx] = *(const u16x8*)(cwp + idx);

  float bias[4];
#pragma unroll
  for (int nn = 0; nn < 4; nn++) bias[nn] = cbp[nn * 16 + l16];

  int e8 = tid & 7;
  int colb = part * 512 + n * 64 + e8 * 8;

  for (int ch = 0; ch < 4; ch++) {
    int t0 = (lt0 + ch) * 128;
    if (ch) __syncthreads();
    for (int r = tid >> 3; r < 134; r += 32) {
      int tt = t0 + r - 3;
      u16x8 v = {0, 0, 0, 0, 0, 0, 0, 0};
      if (tt >= 0 && tt < len)
        v = *(const u16x8*)(Wh + (size_t)((tt + tshift) * 4 + b) * 1536 + colb);
      *(u16x8*)&in_s[r * 64 + ((e8 ^ (r & 7)) << 3)] = v;
    }
    __syncthreads();

    f32x4 acc[2][4];
#pragma unroll
    for (int mt = 0; mt < 2; mt++)
#pragma unroll
      for (int nn = 0; nn < 4; nn++) acc[mt][nn] = (f32x4){0.f, 0.f, 0.f, 0.f};

#pragma unroll
    for (int s = 0; s < 7; s++) {
#pragma unroll
      for (int ks = 0; ks < 2; ks++) {
        int eb = ks * 4 + quad;
        s16x8 af[2];
#pragma unroll
        for (int mt = 0; mt < 2; mt++) {
          int r = wave * 32 + mt * 16 + l16 + s;
          af[mt] = *(const s16x8*)&in_s[r * 64 + ((eb ^ (r & 7)) << 3)];
        }
#pragma unroll
        for (int nn = 0; nn < 4; nn++) {
          int d = nn * 16 + l16;
          s16x8 bf = *(const s16x8*)&wT_s[s * 4096 + d * 64 + ((eb ^ (d & 7)) << 3)];
          acc[0][nn] = MFMA_B16(af[0], bf, acc[0][nn]);
          acc[1][nn] = MFMA_B16(af[1], bf, acc[1][nn]);
        }
      }
    }

    if (!vt) {
#pragma unroll
      for (int mt = 0; mt < 2; mt++)
#pragma unroll
        for (int nn = 0; nn < 4; nn++) {
          int col = nn * 16 + l16;
#pragma unroll
          for (int reg = 0; reg < 4; reg++) {
            int t = t0 + wave * 32 + mt * 16 + quad * 4 + reg;
            outp[(size_t)((t * 4 + b) * 8 + n) * 64 + col] = f2b(acc[mt][nn][reg] + bias[nn]);
          }
        }
    } else {
      __syncthreads();
      u16* T = in_s;
#pragma unroll
      for (int mt = 0; mt < 2; mt++)
#pragma unroll
        for (int nn = 0; nn < 4; nn++) {
          union { u32 u[2]; u16x4 v; } pk;
          pk.u[0] = f2b2(acc[mt][nn][0] + bias[nn], acc[mt][nn][1] + bias[nn]);
          pk.u[1] = f2b2(acc[mt][nn][2] + bias[nn], acc[mt][nn][3] + bias[nn]);
          *(u16x4*)&T[(nn * 16 + l16) * 132 + wave * 32 + mt * 16 + quad * 4] = pk.v;
        }
      __syncthreads();
      int dS = tid >> 2, tq = tid & 3;
      u16* gdst = outp + ((size_t)(b * 8 + n) * 64 + dS) * 2048 + t0 + tq * 32;
      const u16* tsrc = &T[dS * 132 + tq * 32];
#pragma unroll
      for (int c = 0; c < 4; c++)
        *(u16x8*)(gdst + c * 8) = *(const u16x8*)(tsrc + c * 8);
    }
  }
}

// ---------------------------------------------------------------------------
// MFMA flash attention — EXACT R8 (66.5 µs). Untouched.
// ---------------------------------------------------------------------------
__global__ __launch_bounds__(256) void attn_mfma(
    const u16* __restrict__ qpost, const u16* __restrict__ kpost,
    const u16* __restrict__ vpostT, const u16* __restrict__ Rk,
    const float* __restrict__ rwb, const float* __restrict__ rrb,
    u16* __restrict__ av_out) {
  __shared__ u16 K_s[64 * 64];
  __shared__ u16 V_s[64 * 64];
  __shared__ u16 R_s[128 * 64];
  __shared__ u16 BD_s[4][80 * 20];
  __shared__ u16 P_s[4][16 * 64];
  int tid = threadIdx.x;
  int xc = blockIdx.x;                  // 0..31 = b*8+n
  int y  = blockIdx.y;                  // 0..15
  int it = (y < 8) ? y : 23 - y;        // complementary pairing across +8
  int i0 = it * 64;
  int b = xc >> 3, n = xc & 7;
  int wave = tid >> 6, lane = tid & 63, quad = lane >> 4, l16 = lane & 15;
  int i0w = i0 + wave * 16;
  int rbaseW = 48 - wave * 16;
  int rbase = 960 - i0;
  int ntiles = it + 17;
  const float SC = 0.125f * 1.44269504f;

  s16x8 aw[2], ar[2];
  {
    int ig = i0w + l16;
    const u16* qp = qpost + ((size_t)((ig * 4 + b) * 8 + n)) * 64;
#pragma unroll
    for (int ks = 0; ks < 2; ks++) {
      int d0 = ks * 32 + quad * 8;
      u16x8 qv = *(const u16x8*)(qp + d0);
      union { u32x4 u; s16x8 s; } pw, pr;
#pragma unroll
      for (int e2 = 0; e2 < 4; e2++) {
        float qa = b2f(qv[2 * e2]), qb = b2f(qv[2 * e2 + 1]);
        pw.u[e2] = f2b2(qa + rwb[n * 64 + d0 + 2 * e2], qb + rwb[n * 64 + d0 + 2 * e2 + 1]);
        pr.u[e2] = f2b2(qa + rrb[n * 64 + d0 + 2 * e2], qb + rrb[n * 64 + d0 + 2 * e2 + 1]);
      }
      aw[ks] = pw.s;
      ar[ks] = pr.s;
    }
  }

  {
    int rrI = tid >> 1, h = tid & 1;
    int g = rbase + rrI;
    int prow = g & 127;
    const u16* rp2 = Rk + (size_t)g * 512 + n * 64 + h * 32;
#pragma unroll
    for (int c = 0; c < 4; c++) {
      int kb = h * 4 + c;
      *(u16x8*)&R_s[prow * 64 + ((kb ^ (prow & 7)) << 3)] = *(const u16x8*)(rp2 + c * 8);
    }
  }

  f32x4 O[4];
#pragma unroll
  for (int c = 0; c < 4; c++) O[c] = (f32x4){0.f, 0.f, 0.f, 0.f};
  float l4[4] = {0.f, 0.f, 0.f, 0.f};

  int jl = tid >> 2, q4 = tid & 3;
  u16x8 kv0, kv1, vv0, vv1, rv0, rv1;
  {
    size_t src = ((size_t)(jl * 4 + b) * 8 + n) * 64 + q4 * 16;
    kv0 = *(const u16x8*)(kpost + src);
    kv1 = *(const u16x8*)(kpost + src + 8);
    const u16* vsrc = vpostT + ((size_t)(b * 8 + n) * 64 + jl) * 2048 + q4 * 16;
    vv0 = *(const u16x8*)(vsrc);
    vv1 = *(const u16x8*)(vsrc + 8);
  }
  {
    int g = rbase + 128 + jl;
    rv0 = (u16x8){0, 0, 0, 0, 0, 0, 0, 0};
    rv1 = rv0;
    if (g < 2048) {
      const u16* rp2 = Rk + (size_t)g * 512 + n * 64 + q4 * 16;
      rv0 = *(const u16x8*)(rp2);
      rv1 = *(const u16x8*)(rp2 + 8);
    }
  }

  for (int t = 0; t < ntiles; t++) {
    int j0 = t * 64;
    __syncthreads();
    *(u16x8*)&K_s[jl * 64 + (((2 * q4) ^ (jl & 7)) << 3)] = kv0;
    *(u16x8*)&K_s[jl * 64 + (((2 * q4 + 1) ^ (jl & 7)) << 3)] = kv1;
    *(u16x8*)&V_s[jl * 64 + (((2 * q4) ^ (jl & 7)) << 3)] = vv0;
    *(u16x8*)&V_s[jl * 64 + (((2 * q4 + 1) ^ (jl & 7)) << 3)] = vv1;
    if (t > 0) {
      int g = rbase + j0 + 64 + jl;
      int prow = g & 127;
      *(u16x8*)&R_s[prow * 64 + (((2 * q4) ^ (prow & 7)) << 3)] = rv0;
      *(u16x8*)&R_s[prow * 64 + (((2 * q4 + 1) ^ (prow & 7)) << 3)] = rv1;
    }
    __syncthreads();

    if (t + 1 < ntiles) {
      int j0n = j0 + 64;
      size_t src = ((size_t)((j0n + jl) * 4 + b) * 8 + n) * 64 + q4 * 16;
      kv0 = *(const u16x8*)(kpost + src);
      kv1 = *(const u16x8*)(kpost + src + 8);
      const u16* vsrc = vpostT + ((size_t)(b * 8 + n) * 64 + jl) * 2048 + j0n + q4 * 16;
      vv0 = *(const u16x8*)(vsrc);
      vv1 = *(const u16x8*)(vsrc + 8);
      int g = rbase + j0n + 64 + jl;
      rv0 = (u16x8){0, 0, 0, 0, 0, 0, 0, 0};
      rv1 = rv0;
      if (g < 2048) {
        const u16* rp2 = Rk + (size_t)g * 512 + n * 64 + q4 * 16;
        rv0 = *(const u16x8*)(rp2);
        rv1 = *(const u16x8*)(rp2 + 8);
      }
    }

    f32x4 sc4[4];
#pragma unroll
    for (int c = 0; c < 4; c++) {
      f32x4 tt = (f32x4){0.f, 0.f, 0.f, 0.f};
#pragma unroll
      for (int ks = 0; ks < 2; ks++) {
        int j = c * 16 + l16;
        int kb = ks * 4 + quad;
        s16x8 kf = *(const s16x8*)&K_s[j * 64 + ((kb ^ (j & 7)) << 3)];
        tt = MFMA_B16(aw[ks], kf, tt);
      }
      sc4[c] = tt;
    }
    int rbj = rbase + j0 + rbaseW;
#pragma unroll
    for (int cb = 0; cb < 5; cb++) {
      f32x4 tt = (f32x4){0.f, 0.f, 0.f, 0.f};
#pragma unroll
      for (int ks = 0; ks < 2; ks++) {
        int prow = (rbj + cb * 16 + l16) & 127;
        int kb = ks * 4 + quad;
        s16x8 rf = *(const s16x8*)&R_s[prow * 64 + ((kb ^ (prow & 7)) << 3)];
        tt = MFMA_B16(ar[ks], rf, tt);
      }
      union { u32 u[2]; u16x4 v; } pk;
      pk.u[0] = f2b2(tt[0], tt[1]);
      pk.u[1] = f2b2(tt[2], tt[3]);
      *(u16x4*)&BD_s[wave][(cb * 16 + l16) * 20 + quad * 4] = pk.v;
    }

#pragma unroll
    for (int c = 0; c < 4; c++)
#pragma unroll
      for (int reg = 0; reg < 4; reg++) {
        int iw = quad * 4 + reg;
        int uw = c * 16 + l16 + 15 - iw;
        float bd = b2f(BD_s[wave][uw * 20 + iw]);
        float val = (sc4[c][reg] + bd) * SC;
        int jg = j0 + c * 16 + l16;
        float p = (jg > i0w + iw + 1024) ? 0.f : __builtin_amdgcn_exp2f(val);
        l4[reg] += p;
        int jb = c * 2 + (l16 >> 3);
        P_s[wave][iw * 64 + ((jb ^ (iw & 7)) << 3) + (l16 & 7)] = f2b(p);
      }

#pragma unroll
    for (int cd = 0; cd < 4; cd++) {
      int d = cd * 16 + l16;
#pragma unroll
      for (int ks = 0; ks < 2; ks++) {
        int kb = ks * 4 + quad;
        s16x8 pf = *(const s16x8*)&P_s[wave][l16 * 64 + ((kb ^ (l16 & 7)) << 3)];
        s16x8 vf = *(const s16x8*)&V_s[d * 64 + ((kb ^ (d & 7)) << 3)];
        O[cd] = MFMA_B16(pf, vf, O[cd]);
      }
    }
  }

#pragma unroll
  for (int off = 1; off < 16; off <<= 1)
#pragma unroll
    for (int reg = 0; reg < 4; reg++) l4[reg] += __shfl_xor(l4[reg], off);

#pragma unroll
  for (int reg = 0; reg < 4; reg++) {
    float inv = 1.0f / l4[reg];
    int ig2 = i0w + quad * 4 + reg;
#pragma unroll
    for (int cd = 0; cd < 4; cd++)
      av_out[((size_t)(ig2 * 4 + b)) * 512 + n * 64 + cd * 16 + l16] =
          f2b(O[cd][reg] * inv);
  }
}

// ---------------------------------------------------------------------------
extern "C" void kernel_launch(void* const* d_in, const int* in_sizes, int n_in,
                              void* d_out, int out_size, void* d_ws, size_t ws_size,
                              hipStream_t stream) {
  (void)in_sizes; (void)n_in; (void)out_size;
  const float* w    = (const float*)d_in[0];
  const float* r    = (const float*)d_in[1];
  const float* mems = (const float*)d_in[2];
  const float* rwb  = (const float*)d_in[3];
  const float* rrb  = (const float*)d_in[4];
  const float* qkvW = (const float*)d_in[5];
  const float* rW   = (const float*)d_in[6];
  const float* cqw  = (const float*)d_in[7];
  const float* cqb  = (const float*)d_in[8];
  const float* ckw  = (const float*)d_in[9];
  const float* ckb  = (const float*)d_in[10];
  const float* cvw  = (const float*)d_in[11];
  const float* cvb  = (const float*)d_in[12];
  const float* oW   = (const float*)d_in[13];
  const float* lng  = (const float*)d_in[14];
  const float* lnb  = (const float*)d_in[15];
  // d_in[16] = attn_mask: deterministic (j > i + MEM_LEN), computed inline.

  u16* ws     = (u16*)d_ws;                 // bf16 intermediates (u16 offsets)
  u16* Wh     = ws;                         // 8192x1536
  u16* qpost  = Wh + 12582912;              // 1024*4*512; rb aliases (dead before conv q)
  u16* kpost  = qpost + 2097152;            // 2048*4*512
  u16* vpostT = kpost + 4194304;            // [b][n][d][t]
  u16* Rk     = vpostT + 4194304;           // 2048*512
  u16* av     = Rk + 1048576;               // 4096*512; catb aliases av+aout
  u16* aout   = av + 2097152;               // 4096*512 (now unused; kept for layout)
  u16* qkvWb  = aout + 2097152;             // 1536*512
  u16* rWb    = qkvWb + 786432;             // 512*512
  u16* oWb    = rWb + 262144;               // 512*512
  u16* cwb    = oWb + 262144;               // 3*28672 pre-swizzled conv weights
  u16* catb   = av;                         // 8192*512 = av+aout (dead after GEMMs)
  u16* rb     = qpost;                      // 2048*512 <= qpost (dead before conv q)
  if (ws_size < 59416576ull) return;        // diagnostic: absmax==4.9375 -> ws too small

  // 0) fp32 -> bf16 conversions (activations/weights + swizzled conv weights)
  cvt_all<<<3536, 256, 0, stream>>>(mems, w, r, qkvW, rW, oW, cqw, ckw, cvw,
                                    catb, rb, qkvWb, rWb, oWb, cwb);
  // 1+2) fused: w_heads = cat @ qkv_W^T  AND  r_head_k = r @ r_W^T
  gemm_fused<<<dim3(13, 64), 256, 0, stream>>>(catb, qkvWb, Wh, rb, rWb, Rk);
  // 3) fused MFMA head convs (weights staged once, 4 t-chunks per block)
  conv_fused<<<dim3(10, 4, 8), 256, 0, stream>>>(Wh, cwb, cqb, ckb, cvb, qpost, kpost, vpostT);
  // 4) MFMA rel-attention (R8 core, balanced block->CU pairing)
  attn_mfma<<<dim3(32, 16), 256, 0, stream>>>(qpost, kpost, vpostT, Rk, rwb, rrb, av);
  // 5+6) fused: out = LayerNorm(w + av @ o_W^T)
  oproj_ln<<<256, 256, 0, stream>>>(av, oWb, w, lng, lnb, (float*)d_out);
}

// Round 14
// 227.624 us; speedup vs baseline: 1.0111x; 1.0111x over previous
//
#include <hip/hip_runtime.h>
#include <hip/hip_bf16.h>

typedef unsigned short u16;
typedef unsigned int   u32;
typedef u16 u16x8 __attribute__((ext_vector_type(8)));
typedef u16 u16x4 __attribute__((ext_vector_type(4)));
typedef float f32x4 __attribute__((ext_vector_type(4)));
typedef short s16x8 __attribute__((ext_vector_type(8)));
typedef u32 u32x4 __attribute__((ext_vector_type(4)));

__device__ __forceinline__ float b2f(u16 u) { return __uint_as_float(((u32)u) << 16); }
__device__ __forceinline__ u16 f2b(float f) {
  u32 u = __float_as_uint(f);
  u32 r = u + 0x7FFFu + ((u >> 16) & 1u);
  return (u16)(r >> 16);
}
__device__ __forceinline__ u32 f2b2(float lo, float hi) {
  __hip_bfloat162 h = __float22bfloat162_rn(make_float2(lo, hi));
  union { __hip_bfloat162 h; u32 u; } cv;
  cv.h = h;
  return cv.u;
}

#define MFMA_B16(A, B, C) __builtin_amdgcn_mfma_f32_16x16x32_bf16((A), (B), (C), 0, 0, 0)

// async global->LDS, 16B per lane; LDS dest is wave-uniform base + lane*16.
__device__ __forceinline__ void gl16(const u16* g, u16* l) {
  __builtin_amdgcn_global_load_lds(
      (const __attribute__((address_space(1))) void*)g,
      (__attribute__((address_space(3))) void*)l, 16, 0, 0);
}

// ---------------------------------------------------------------------------
// fp32 -> bf16 convert pass (cvt_w folded in at blocks >= 3200). R8-exact.
// ---------------------------------------------------------------------------
__global__ __launch_bounds__(256) void cvt_all(
    const float* __restrict__ mems, const float* __restrict__ w,
    const float* __restrict__ r, const float* __restrict__ qkvW,
    const float* __restrict__ rW, const float* __restrict__ oW,
    const float* __restrict__ cqw, const float* __restrict__ ckw,
    const float* __restrict__ cvw,
    u16* __restrict__ catb, u16* __restrict__ rb, u16* __restrict__ qkvWb,
    u16* __restrict__ rWb, u16* __restrict__ oWb, u16* __restrict__ cwb) {
  if (blockIdx.x >= 3200) {
    int idx = (blockIdx.x - 3200) * 256 + threadIdx.x;   // 0..86015
    if (idx >= 86016) return;
    int wsel = idx / 28672, rem = idx % 28672;
    const float* src = (wsel == 0) ? cqw : ((wsel == 1) ? ckw : cvw);
    int s = rem / 4096, r2 = rem % 4096;
    int d = r2 / 64, eswz = r2 % 64;
    int e = (((eswz >> 3) ^ (d & 7)) << 3) + (eswz & 7);
    cwb[idx] = f2b(src[d * 448 + e * 7 + s]);
    return;
  }
  long g = ((long)blockIdx.x * 256 + threadIdx.x) * 8;
  const float* src;
  u16* dst;
  if (g < 4194304) {
    src = (g < 2097152) ? (mems + g) : (w + (g - 2097152));
    dst = catb + g;
  } else if (g < 5242880) {
    src = r + (g - 4194304);    dst = rb + (g - 4194304);
  } else if (g < 6029312) {
    src = qkvW + (g - 5242880); dst = qkvWb + (g - 5242880);
  } else if (g < 6291456) {
    src = rW + (g - 6029312);   dst = rWb + (g - 6029312);
  } else {
    src = oW + (g - 6291456);   dst = oWb + (g - 6291456);
  }
  f32x4 a = *(const f32x4*)src;
  f32x4 b = *(const f32x4*)(src + 4);
  u32x4 p = (u32x4){f2b2(a[0], a[1]), f2b2(a[2], a[3]),
                    f2b2(b[0], b[1]), f2b2(b[2], b[3])};
  *(u32x4*)dst = p;
}

// ---------------------------------------------------------------------------
// Fused MFMA GEMM (R8-exact): 128x128 tiles, global_load_lds staging, q-skip.
// ---------------------------------------------------------------------------
__global__ __launch_bounds__(256) void gemm_fused(
    const u16* __restrict__ catb, const u16* __restrict__ qkvWb,
    u16* __restrict__ Wh, const u16* __restrict__ rb,
    const u16* __restrict__ rWb, u16* __restrict__ Rk) {
  int bx = blockIdx.x, by = blockIdx.y;
  const u16 *A, *B;
  u16* C;
  int N;
  if (bx < 12) {
    if (bx < 4 && by < 32) return;   // q-cols of mems rows never read
    A = catb; B = qkvWb; C = Wh; N = 1536;
  } else {
    if (by >= 16) return;
    A = rb; B = rWb; C = Rk; N = 512; bx = 0;
  }
  const int K = 512;
  __shared__ u16 A_s[128 * 32];
  __shared__ u16 B_s[128 * 32];
  int tid = threadIdx.x;
  int wave = tid >> 6, lane = tid & 63, quad = lane >> 4, l16 = lane & 15;
  int wr = wave >> 1, wc = wave & 1;

  f32x4 acc[4][4];
#pragma unroll
  for (int a = 0; a < 4; a++)
#pragma unroll
    for (int bb = 0; bb < 4; bb++) acc[a][bb] = (f32x4){0.f, 0.f, 0.f, 0.f};

  const u16* Ab = A + (size_t)by * 128 * K;
  const u16* Bb = B + (size_t)bx * 128 * K;
  int lrow = lane >> 2;
  int lkc  = (lane & 3) * 8;
  int L0 = wave * 2;

  for (int k0 = 0; k0 < K; k0 += 32) {
    __syncthreads();
#pragma unroll
    for (int m = 0; m < 2; m++) {
      int L = L0 + m;
      int row = L * 16 + lrow;
      gl16(Ab + (size_t)row * K + k0 + lkc, &A_s[L * 512 + lane * 8]);
      gl16(Bb + (size_t)row * K + k0 + lkc, &B_s[L * 512 + lane * 8]);
    }
    __syncthreads();

    s16x8 af[4], bf[4];
#pragma unroll
    for (int a = 0; a < 4; a++)
      af[a] = *(const s16x8*)&A_s[(wr * 64 + a * 16 + l16) * 32 + quad * 8];
#pragma unroll
    for (int bb = 0; bb < 4; bb++)
      bf[bb] = *(const s16x8*)&B_s[(wc * 64 + bb * 16 + l16) * 32 + quad * 8];
#pragma unroll
    for (int a = 0; a < 4; a++)
#pragma unroll
      for (int bb = 0; bb < 4; bb++)
        acc[a][bb] = MFMA_B16(af[a], bf[bb], acc[a][bb]);
  }

#pragma unroll
  for (int a = 0; a < 4; a++)
#pragma unroll
    for (int bb = 0; bb < 4; bb++) {
      int row = by * 128 + wr * 64 + a * 16 + quad * 4;
      int col = bx * 128 + wc * 64 + bb * 16 + l16;
#pragma unroll
      for (int reg = 0; reg < 4; reg++)
        C[(size_t)(row + reg) * N + col] = f2b(acc[a][bb][reg]);
    }
}

// ---------------------------------------------------------------------------
// Standalone o-proj GEMM (R12-exact): 64x128 tiles -> grid (4,64) = 256
// blocks (full GPU). Consumer of attn; cannot perturb attn inputs.
// ---------------------------------------------------------------------------
__global__ __launch_bounds__(256) void gemm_mfma(
    const u16* __restrict__ A, const u16* __restrict__ B,
    u16* __restrict__ C, int N, int K) {
  __shared__ u16 A_s[64 * 32];
  __shared__ u16 B_s[128 * 32];
  int tid = threadIdx.x;
  int bx = blockIdx.x, by = blockIdx.y;
  int wave = tid >> 6, lane = tid & 63, quad = lane >> 4, l16 = lane & 15;
  int lrow = lane >> 2;
  int lkc  = (lane & 3) * 8;
  int L0 = wave * 2;

  f32x4 acc[4][2];
#pragma unroll
  for (int a = 0; a < 4; a++)
#pragma unroll
    for (int bb = 0; bb < 2; bb++) acc[a][bb] = (f32x4){0.f, 0.f, 0.f, 0.f};

  const u16* Ab = A + (size_t)by * 64 * K;
  const u16* Bb = B + (size_t)bx * 128 * K;

  for (int k0 = 0; k0 < K; k0 += 32) {
    __syncthreads();
    gl16(Ab + (size_t)(wave * 16 + lrow) * K + k0 + lkc, &A_s[wave * 512 + lane * 8]);
#pragma unroll
    for (int m = 0; m < 2; m++) {
      int L = L0 + m;
      int row = L * 16 + lrow;
      gl16(Bb + (size_t)row * K + k0 + lkc, &B_s[L * 512 + lane * 8]);
    }
    __syncthreads();

    s16x8 af[4], bf[2];
#pragma unroll
    for (int a = 0; a < 4; a++)
      af[a] = *(const s16x8*)&A_s[(a * 16 + l16) * 32 + quad * 8];
#pragma unroll
    for (int bb = 0; bb < 2; bb++)
      bf[bb] = *(const s16x8*)&B_s[(wave * 32 + bb * 16 + l16) * 32 + quad * 8];
#pragma unroll
    for (int a = 0; a < 4; a++)
#pragma unroll
      for (int bb = 0; bb < 2; bb++)
        acc[a][bb] = MFMA_B16(af[a], bf[bb], acc[a][bb]);
  }

#pragma unroll
  for (int a = 0; a < 4; a++)
#pragma unroll
    for (int bb = 0; bb < 2; bb++) {
      int row = by * 64 + a * 16 + quad * 4;
      int col = bx * 128 + wave * 32 + bb * 16 + l16;
#pragma unroll
      for (int reg = 0; reg < 4; reg++)
        C[(size_t)(row + reg) * N + col] = f2b(acc[a][bb][reg]);
    }
}

// ---------------------------------------------------------------------------
// Fused MFMA conv (R8-exact: weights staged once, 4 t-chunks/block,
// grid (10,4,8)).
// ---------------------------------------------------------------------------
__global__ __launch_bounds__(256) void conv_fused(
    const u16* __restrict__ Wh, const u16* __restrict__ cwb,
    const float* __restrict__ cqb, const float* __restrict__ ckb,
    const float* __restrict__ cvb,
    u16* __restrict__ qpost, u16* __restrict__ kpost, u16* __restrict__ vpostT) {
  __shared__ u16 wT_s[7 * 4096];
  __shared__ u16 in_s[134 * 64];   // input window; reused as v-transpose T
  int blk = blockIdx.x;
  int part, lt0, len, tshift, vt;
  const float* cbp;
  const u16* cwp;
  u16* outp;
  if (blk < 2) {
    part = 0; lt0 = blk * 4; len = 1024; tshift = 1024; vt = 0;
    cbp = cqb; cwp = cwb; outp = qpost;
  } else if (blk < 6) {
    part = 1; lt0 = (blk - 2) * 4; len = 2048; tshift = 0; vt = 0;
    cbp = ckb; cwp = cwb + 28672; outp = kpost;
  } else {
    part = 2; lt0 = (blk - 6) * 4; len = 2048; tshift = 0; vt = 1;
    cbp = cvb; cwp = cwb + 57344; outp = vpostT;
  }
  int tid = threadIdx.x;
  int b = blockIdx.y, n = blockIdx.z;
  int wave = tid >> 6, lane = tid & 63, quad = lane >> 4, l16 = lane & 15;

  for (int idx = tid * 8; idx < 28672; idx += 2048)
    *(u16x8*)&wT_s[idx] = *(const u16x8*)(cwp + idx);

  float bias[4];
#pragma unroll
  for (int nn = 0; nn < 4; nn++) bias[nn] = cbp[nn * 16 + l16];

  int e8 = tid & 7;
  int colb = part * 512 + n * 64 + e8 * 8;

  for (int ch = 0; ch < 4; ch++) {
    int t0 = (lt0 + ch) * 128;
    if (ch) __syncthreads();
    for (int r = tid >> 3; r < 134; r += 32) {
      int tt = t0 + r - 3;
      u16x8 v = {0, 0, 0, 0, 0, 0, 0, 0};
      if (tt >= 0 && tt < len)
        v = *(const u16x8*)(Wh + (size_t)((tt + tshift) * 4 + b) * 1536 + colb);
      *(u16x8*)&in_s[r * 64 + ((e8 ^ (r & 7)) << 3)] = v;
    }
    __syncthreads();

    f32x4 acc[2][4];
#pragma unroll
    for (int mt = 0; mt < 2; mt++)
#pragma unroll
      for (int nn = 0; nn < 4; nn++) acc[mt][nn] = (f32x4){0.f, 0.f, 0.f, 0.f};

#pragma unroll
    for (int s = 0; s < 7; s++) {
#pragma unroll
      for (int ks = 0; ks < 2; ks++) {
        int eb = ks * 4 + quad;
        s16x8 af[2];
#pragma unroll
        for (int mt = 0; mt < 2; mt++) {
          int r = wave * 32 + mt * 16 + l16 + s;
          af[mt] = *(const s16x8*)&in_s[r * 64 + ((eb ^ (r & 7)) << 3)];
        }
#pragma unroll
        for (int nn = 0; nn < 4; nn++) {
          int d = nn * 16 + l16;
          s16x8 bf = *(const s16x8*)&wT_s[s * 4096 + d * 64 + ((eb ^ (d & 7)) << 3)];
          acc[0][nn] = MFMA_B16(af[0], bf, acc[0][nn]);
          acc[1][nn] = MFMA_B16(af[1], bf, acc[1][nn]);
        }
      }
    }

    if (!vt) {
#pragma unroll
      for (int mt = 0; mt < 2; mt++)
#pragma unroll
        for (int nn = 0; nn < 4; nn++) {
          int col = nn * 16 + l16;
#pragma unroll
          for (int reg = 0; reg < 4; reg++) {
            int t = t0 + wave * 32 + mt * 16 + quad * 4 + reg;
            outp[(size_t)((t * 4 + b) * 8 + n) * 64 + col] = f2b(acc[mt][nn][reg] + bias[nn]);
          }
        }
    } else {
      __syncthreads();
      u16* T = in_s;
#pragma unroll
      for (int mt = 0; mt < 2; mt++)
#pragma unroll
        for (int nn = 0; nn < 4; nn++) {
          union { u32 u[2]; u16x4 v; } pk;
          pk.u[0] = f2b2(acc[mt][nn][0] + bias[nn], acc[mt][nn][1] + bias[nn]);
          pk.u[1] = f2b2(acc[mt][nn][2] + bias[nn], acc[mt][nn][3] + bias[nn]);
          *(u16x4*)&T[(nn * 16 + l16) * 132 + wave * 32 + mt * 16 + quad * 4] = pk.v;
        }
      __syncthreads();
      int dS = tid >> 2, tq = tid & 3;
      u16* gdst = outp + ((size_t)(b * 8 + n) * 64 + dS) * 2048 + t0 + tq * 32;
      const u16* tsrc = &T[dS * 132 + tq * 32];
#pragma unroll
      for (int c = 0; c < 4; c++)
        *(u16x8*)(gdst + c * 8) = *(const u16x8*)(tsrc + c * 8);
    }
  }
}

// ---------------------------------------------------------------------------
// MFMA flash attention — EXACT R8 (66.6 µs, balanced complementary pairing
// + L2-aligned (b,n)-major mapping). Untouched.
// ---------------------------------------------------------------------------
__global__ __launch_bounds__(256) void attn_mfma(
    const u16* __restrict__ qpost, const u16* __restrict__ kpost,
    const u16* __restrict__ vpostT, const u16* __restrict__ Rk,
    const float* __restrict__ rwb, const float* __restrict__ rrb,
    u16* __restrict__ av_out) {
  __shared__ u16 K_s[64 * 64];
  __shared__ u16 V_s[64 * 64];
  __shared__ u16 R_s[128 * 64];
  __shared__ u16 BD_s[4][80 * 20];
  __shared__ u16 P_s[4][16 * 64];
  int tid = threadIdx.x;
  int xc = blockIdx.x;                  // 0..31 = b*8+n
  int y  = blockIdx.y;                  // 0..15
  int it = (y < 8) ? y : 23 - y;        // complementary pairing across +8
  int i0 = it * 64;
  int b = xc >> 3, n = xc & 7;
  int wave = tid >> 6, lane = tid & 63, quad = lane >> 4, l16 = lane & 15;
  int i0w = i0 + wave * 16;
  int rbaseW = 48 - wave * 16;
  int rbase = 960 - i0;
  int ntiles = it + 17;
  const float SC = 0.125f * 1.44269504f;

  s16x8 aw[2], ar[2];
  {
    int ig = i0w + l16;
    const u16* qp = qpost + ((size_t)((ig * 4 + b) * 8 + n)) * 64;
#pragma unroll
    for (int ks = 0; ks < 2; ks++) {
      int d0 = ks * 32 + quad * 8;
      u16x8 qv = *(const u16x8*)(qp + d0);
      union { u32x4 u; s16x8 s; } pw, pr;
#pragma unroll
      for (int e2 = 0; e2 < 4; e2++) {
        float qa = b2f(qv[2 * e2]), qb = b2f(qv[2 * e2 + 1]);
        pw.u[e2] = f2b2(qa + rwb[n * 64 + d0 + 2 * e2], qb + rwb[n * 64 + d0 + 2 * e2 + 1]);
        pr.u[e2] = f2b2(qa + rrb[n * 64 + d0 + 2 * e2], qb + rrb[n * 64 + d0 + 2 * e2 + 1]);
      }
      aw[ks] = pw.s;
      ar[ks] = pr.s;
    }
  }

  {
    int rrI = tid >> 1, h = tid & 1;
    int g = rbase + rrI;
    int prow = g & 127;
    const u16* rp2 = Rk + (size_t)g * 512 + n * 64 + h * 32;
#pragma unroll
    for (int c = 0; c < 4; c++) {
      int kb = h * 4 + c;
      *(u16x8*)&R_s[prow * 64 + ((kb ^ (prow & 7)) << 3)] = *(const u16x8*)(rp2 + c * 8);
    }
  }

  f32x4 O[4];
#pragma unroll
  for (int c = 0; c < 4; c++) O[c] = (f32x4){0.f, 0.f, 0.f, 0.f};
  float l4[4] = {0.f, 0.f, 0.f, 0.f};

  int jl = tid >> 2, q4 = tid & 3;
  u16x8 kv0, kv1, vv0, vv1, rv0, rv1;
  {
    size_t src = ((size_t)(jl * 4 + b) * 8 + n) * 64 + q4 * 16;
    kv0 = *(const u16x8*)(kpost + src);
    kv1 = *(const u16x8*)(kpost + src + 8);
    const u16* vsrc = vpostT + ((size_t)(b * 8 + n) * 64 + jl) * 2048 + q4 * 16;
    vv0 = *(const u16x8*)(vsrc);
    vv1 = *(const u16x8*)(vsrc + 8);
  }
  {
    int g = rbase + 128 + jl;
    rv0 = (u16x8){0, 0, 0, 0, 0, 0, 0, 0};
    rv1 = rv0;
    if (g < 2048) {
      const u16* rp2 = Rk + (size_t)g * 512 + n * 64 + q4 * 16;
      rv0 = *(const u16x8*)(rp2);
      rv1 = *(const u16x8*)(rp2 + 8);
    }
  }

  for (int t = 0; t < ntiles; t++) {
    int j0 = t * 64;
    __syncthreads();
    *(u16x8*)&K_s[jl * 64 + (((2 * q4) ^ (jl & 7)) << 3)] = kv0;
    *(u16x8*)&K_s[jl * 64 + (((2 * q4 + 1) ^ (jl & 7)) << 3)] = kv1;
    *(u16x8*)&V_s[jl * 64 + (((2 * q4) ^ (jl & 7)) << 3)] = vv0;
    *(u16x8*)&V_s[jl * 64 + (((2 * q4 + 1) ^ (jl & 7)) << 3)] = vv1;
    if (t > 0) {
      int g = rbase + j0 + 64 + jl;
      int prow = g & 127;
      *(u16x8*)&R_s[prow * 64 + (((2 * q4) ^ (prow & 7)) << 3)] = rv0;
      *(u16x8*)&R_s[prow * 64 + (((2 * q4 + 1) ^ (prow & 7)) << 3)] = rv1;
    }
    __syncthreads();

    if (t + 1 < ntiles) {
      int j0n = j0 + 64;
      size_t src = ((size_t)((j0n + jl) * 4 + b) * 8 + n) * 64 + q4 * 16;
      kv0 = *(const u16x8*)(kpost + src);
      kv1 = *(const u16x8*)(kpost + src + 8);
      const u16* vsrc = vpostT + ((size_t)(b * 8 + n) * 64 + jl) * 2048 + j0n + q4 * 16;
      vv0 = *(const u16x8*)(vsrc);
      vv1 = *(const u16x8*)(vsrc + 8);
      int g = rbase + j0n + 64 + jl;
      rv0 = (u16x8){0, 0, 0, 0, 0, 0, 0, 0};
      rv1 = rv0;
      if (g < 2048) {
        const u16* rp2 = Rk + (size_t)g * 512 + n * 64 + q4 * 16;
        rv0 = *(const u16x8*)(rp2);
        rv1 = *(const u16x8*)(rp2 + 8);
      }
    }

    f32x4 sc4[4];
#pragma unroll
    for (int c = 0; c < 4; c++) {
      f32x4 tt = (f32x4){0.f, 0.f, 0.f, 0.f};
#pragma unroll
      for (int ks = 0; ks < 2; ks++) {
        int j = c * 16 + l16;
        int kb = ks * 4 + quad;
        s16x8 kf = *(const s16x8*)&K_s[j * 64 + ((kb ^ (j & 7)) << 3)];
        tt = MFMA_B16(aw[ks], kf, tt);
      }
      sc4[c] = tt;
    }
    int rbj = rbase + j0 + rbaseW;
#pragma unroll
    for (int cb = 0; cb < 5; cb++) {
      f32x4 tt = (f32x4){0.f, 0.f, 0.f, 0.f};
#pragma unroll
      for (int ks = 0; ks < 2; ks++) {
        int prow = (rbj + cb * 16 + l16) & 127;
        int kb = ks * 4 + quad;
        s16x8 rf = *(const s16x8*)&R_s[prow * 64 + ((kb ^ (prow & 7)) << 3)];
        tt = MFMA_B16(ar[ks], rf, tt);
      }
      union { u32 u[2]; u16x4 v; } pk;
      pk.u[0] = f2b2(tt[0], tt[1]);
      pk.u[1] = f2b2(tt[2], tt[3]);
      *(u16x4*)&BD_s[wave][(cb * 16 + l16) * 20 + quad * 4] = pk.v;
    }

#pragma unroll
    for (int c = 0; c < 4; c++)
#pragma unroll
      for (int reg = 0; reg < 4; reg++) {
        int iw = quad * 4 + reg;
        int uw = c * 16 + l16 + 15 - iw;
        float bd = b2f(BD_s[wave][uw * 20 + iw]);
        float val = (sc4[c][reg] + bd) * SC;
        int jg = j0 + c * 16 + l16;
        float p = (jg > i0w + iw + 1024) ? 0.f : __builtin_amdgcn_exp2f(val);
        l4[reg] += p;
        int jb = c * 2 + (l16 >> 3);
        P_s[wave][iw * 64 + ((jb ^ (iw & 7)) << 3) + (l16 & 7)] = f2b(p);
      }

#pragma unroll
    for (int cd = 0; cd < 4; cd++) {
      int d = cd * 16 + l16;
#pragma unroll
      for (int ks = 0; ks < 2; ks++) {
        int kb = ks * 4 + quad;
        s16x8 pf = *(const s16x8*)&P_s[wave][l16 * 64 + ((kb ^ (l16 & 7)) << 3)];
        s16x8 vf = *(const s16x8*)&V_s[d * 64 + ((kb ^ (d & 7)) << 3)];
        O[cd] = MFMA_B16(pf, vf, O[cd]);
      }
    }
  }

#pragma unroll
  for (int off = 1; off < 16; off <<= 1)
#pragma unroll
    for (int reg = 0; reg < 4; reg++) l4[reg] += __shfl_xor(l4[reg], off);

#pragma unroll
  for (int reg = 0; reg < 4; reg++) {
    float inv = 1.0f / l4[reg];
    int ig2 = i0w + quad * 4 + reg;
#pragma unroll
    for (int cd = 0; cd < 4; cd++)
      av_out[((size_t)(ig2 * 4 + b)) * 512 + n * 64 + cd * 16 + l16] =
          f2b(O[cd][reg] * inv);
  }
}

// ---------------------------------------------------------------------------
// out = LayerNorm(w + attn_out)*g + b (R8-exact).
// ---------------------------------------------------------------------------
__global__ __launch_bounds__(64) void lnorm(
    const float* __restrict__ w, const u16* __restrict__ ao,
    const float* __restrict__ g, const float* __restrict__ bb,
    float* __restrict__ out) {
  int row = blockIdx.x, t = threadIdx.x;
  const float* wp = w + (size_t)row * 512 + t * 8;
  const u16* ap = ao + (size_t)row * 512 + t * 8;
  f32x4 w0 = *(const f32x4*)wp;
  f32x4 w1 = *(const f32x4*)(wp + 4);
  u16x8 av = *(const u16x8*)ap;
  float x[8];
  float sum = 0.f;
#pragma unroll
  for (int e = 0; e < 4; e++) {
    x[e] = w0[e] + b2f(av[e]);
    x[4 + e] = w1[e] + b2f(av[4 + e]);
  }
#pragma unroll
  for (int e = 0; e < 8; e++) sum += x[e];
#pragma unroll
  for (int off = 1; off < 64; off <<= 1) sum += __shfl_xor(sum, off);
  float mu = sum * (1.0f / 512.0f);
  float vs = 0.f;
#pragma unroll
  for (int e = 0; e < 8; e++) {
    float d = x[e] - mu;
    vs += d * d;
  }
#pragma unroll
  for (int off = 1; off < 64; off <<= 1) vs += __shfl_xor(vs, off);
  float rs = rsqrtf(vs * (1.0f / 512.0f) + 1e-5f);
  f32x4 g0 = *(const f32x4*)(g + t * 8);
  f32x4 g1 = *(const f32x4*)(g + t * 8 + 4);
  f32x4 b0 = *(const f32x4*)(bb + t * 8);
  f32x4 b1 = *(const f32x4*)(bb + t * 8 + 4);
  f32x4 o0, o1;
#pragma unroll
  for (int e = 0; e < 4; e++) {
    o0[e] = (x[e] - mu) * rs * g0[e] + b0[e];
    o1[e] = (x[4 + e] - mu) * rs * g1[e] + b1[e];
  }
  float* op = out + (size_t)row * 512 + t * 8;
  *(f32x4*)op = o0;
  *(f32x4*)(op + 4) = o1;
}

// ---------------------------------------------------------------------------
extern "C" void kernel_launch(void* const* d_in, const int* in_sizes, int n_in,
                              void* d_out, int out_size, void* d_ws, size_t ws_size,
                              hipStream_t stream) {
  (void)in_sizes; (void)n_in; (void)out_size;
  const float* w    = (const float*)d_in[0];
  const float* r    = (const float*)d_in[1];
  const float* mems = (const float*)d_in[2];
  const float* rwb  = (const float*)d_in[3];
  const float* rrb  = (const float*)d_in[4];
  const float* qkvW = (const float*)d_in[5];
  const float* rW   = (const float*)d_in[6];
  const float* cqw  = (const float*)d_in[7];
  const float* cqb  = (const float*)d_in[8];
  const float* ckw  = (const float*)d_in[9];
  const float* ckb  = (const float*)d_in[10];
  const float* cvw  = (const float*)d_in[11];
  const float* cvb  = (const float*)d_in[12];
  const float* oW   = (const float*)d_in[13];
  const float* lng  = (const float*)d_in[14];
  const float* lnb  = (const float*)d_in[15];
  // d_in[16] = attn_mask: deterministic (j > i + MEM_LEN), computed inline.

  u16* ws     = (u16*)d_ws;                 // bf16 intermediates (u16 offsets)
  u16* Wh     = ws;                         // 8192x1536
  u16* qpost  = Wh + 12582912;              // 1024*4*512; rb aliases (dead before conv q)
  u16* kpost  = qpost + 2097152;            // 2048*4*512
  u16* vpostT = kpost + 4194304;            // [b][n][d][t]
  u16* Rk     = vpostT + 4194304;           // 2048*512
  u16* av     = Rk + 1048576;               // 4096*512; catb aliases av+aout
  u16* aout   = av + 2097152;               // 4096*512
  u16* qkvWb  = aout + 2097152;             // 1536*512
  u16* rWb    = qkvWb + 786432;             // 512*512
  u16* oWb    = rWb + 262144;               // 512*512
  u16* cwb    = oWb + 262144;               // 3*28672 pre-swizzled conv weights
  u16* catb   = av;                         // 8192*512 = av+aout (dead after GEMMs)
  u16* rb     = qpost;                      // 2048*512 <= qpost (dead before conv q)
  if (ws_size < 59416576ull) return;        // diagnostic: absmax==4.9375 -> ws too small

  // 0) fp32 -> bf16 conversions (activations/weights + swizzled conv weights)
  cvt_all<<<3536, 256, 0, stream>>>(mems, w, r, qkvW, rW, oW, cqw, ckw, cvw,
                                    catb, rb, qkvWb, rWb, oWb, cwb);
  // 1+2) fused: w_heads = cat @ qkv_W^T  AND  r_head_k = r @ r_W^T
  gemm_fused<<<dim3(13, 64), 256, 0, stream>>>(catb, qkvWb, Wh, rb, rWb, Rk);
  // 3) fused MFMA head convs (weights staged once, 4 t-chunks per block)
  conv_fused<<<dim3(10, 4, 8), 256, 0, stream>>>(Wh, cwb, cqb, ckb, cvb, qpost, kpost, vpostT);
  // 4) MFMA rel-attention (R8 core, balanced block->CU pairing)
  attn_mfma<<<dim3(32, 16), 256, 0, stream>>>(qpost, kpost, vpostT, Rk, rwb, rrb, av);
  // 5) attn_out = attn_vec @ o_W^T (64-row tiles, 256 blocks = full GPU)
  gemm_mfma<<<dim3(4, 64), 256, 0, stream>>>(av, oWb, aout, 512, 512);
  // 6) out = LayerNorm(w + attn_out)
  lnorm<<<4096, 64, 0, stream>>>(w, aout, lng, lnb, (float*)d_out);
}